// Round 8
// baseline (1120.158 us; speedup 1.0000x reference)
//
#include <hip/hip_runtime.h>

// N=1024, D=16, H=32, 3H=96.  All tensors fp32 (per reference dtypes).

typedef _Float16 hv2 __attribute__((ext_vector_type(2)));

// pack two fp32 -> half2 bits (v_cvt_pkrtz_f16_f32)
__device__ __forceinline__ unsigned pkh(float a, float b) {
    auto t = __builtin_amdgcn_cvt_pkrtz(a, b);   // native return type
    return __builtin_bit_cast(unsigned, t);
}
// dot2: c += a.x*b.x + a.y*b.y   (f16 inputs, f32 accumulate)
#if __has_builtin(__builtin_amdgcn_fdot2)
__device__ __forceinline__ float d2(unsigned a, unsigned b, float c) {
    return __builtin_amdgcn_fdot2(__builtin_bit_cast(hv2, a),
                                  __builtin_bit_cast(hv2, b), c, false);
}
#else
__device__ __forceinline__ float d2(unsigned a, unsigned b, float c) {
    hv2 x = __builtin_bit_cast(hv2, a), y = __builtin_bit_cast(hv2, b);
    return fmaf((float)x.x, (float)y.x, fmaf((float)x.y, (float)y.y, c));
}
#endif
// neighbor (lane^1) via DPP quad_perm(1,0,3,2) -- VALU, no LDS
#if __has_builtin(__builtin_amdgcn_mov_dpp)
__device__ __forceinline__ float nbr1(float v) {
    return __int_as_float(
        __builtin_amdgcn_mov_dpp(__float_as_int(v), 0xB1, 0xF, 0xF, true));
}
#else
__device__ __forceinline__ float nbr1(float v) {
    return __int_as_float(__builtin_amdgcn_ds_swizzle(__float_as_int(v), 0x041F));
}
#endif
// ds_swizzle BitMode broadcast: every lane reads lane (2*J) of its 32-half.
// offset = {xor[14:10]=0, or[9:5]=2J, and[4:0]=0} = (2J)<<5.  Crossbar only.
#define SWZB(x, J) ((unsigned)__builtin_amdgcn_ds_swizzle((int)(x), ((2*(J)) << 5)))
#define BCAST16(dst, s)                                                        \
    do {                                                                       \
        dst[0] = SWZB(s, 0);   dst[1] = SWZB(s, 1);   dst[2] = SWZB(s, 2);     \
        dst[3] = SWZB(s, 3);   dst[4] = SWZB(s, 4);   dst[5] = SWZB(s, 5);     \
        dst[6] = SWZB(s, 6);   dst[7] = SWZB(s, 7);   dst[8] = SWZB(s, 8);     \
        dst[9] = SWZB(s, 9);   dst[10] = SWZB(s, 10); dst[11] = SWZB(s, 11);   \
        dst[12] = SWZB(s, 12); dst[13] = SWZB(s, 13); dst[14] = SWZB(s, 14);   \
        dst[15] = SWZB(s, 15);                                                 \
    } while (0)

// ---------------------------------------------------------------------------
// K1: stage-1 pairwise split.  A[i,h] = sum_d (w[h,d]-w[h,16+d])*x[i,d] + b[h]
//                              B[j,h] = sum_d w[h,16+d]*x[j,d]
// relu(A[i,:]+B[j,:]) reconstructs out1[i,j,:] -- [N,N,H] never materialized.
// ---------------------------------------------------------------------------
__global__ void proj1_kernel(const float* __restrict__ x, const float* __restrict__ w,
                             const float* __restrict__ bias,
                             float* __restrict__ A, float* __restrict__ B) {
    int idx = blockIdx.x * 256 + threadIdx.x;      // 0..32767
    int i = idx >> 5, h = idx & 31;
    float sa = bias[h];
    float sb = 0.f;
#pragma unroll
    for (int d = 0; d < 16; ++d) {
        float xv = x[i * 16 + d];
        float wa = w[h * 32 + d];
        float wb = w[h * 32 + 16 + d];
        sa += (wa - wb) * xv;
        sb += wb * xv;
    }
    A[i * 32 + h] = sa;
    B[i * 32 + h] = sb;
}

__global__ void proj2_kernel(const float* __restrict__ h1, const float* __restrict__ w,
                             const float* __restrict__ bias,
                             float* __restrict__ A, float* __restrict__ B) {
    int idx = blockIdx.x * 256 + threadIdx.x;      // 0..32767
    int i = idx >> 5, h = idx & 31;
    float sa = bias[h];
    float sb = 0.f;
#pragma unroll
    for (int k = 0; k < 32; ++k) {
        float hv = h1[i * 32 + k];
        float wa = w[h * 64 + k];
        float wb = w[h * 64 + 32 + k];
        sa += (wa - wb) * hv;
        sb += wb * hv;
    }
    A[i * 32 + h] = sa;
    B[i * 32 + h] = sb;
}

// ---------------------------------------------------------------------------
// GRU: TWO chains per wave.  Lane l: chain c = l>>5 (relative to block pair),
// hidden index m = l&31.  Lane owns gate rows r_m/z_m/n_m (x- and h-side,
// f16-packed; identical rows in both halves -> weights shared).  o and h are
// broadcast as 16 packed f16 pairs via ds_swizzle BitMode lane-broadcasts
// (per-32-half, so chains stay separate).  Gates + h-update fully in-lane:
// zero readlane, zero shfl, zero divergence.  Next step's o-broadcast and
// X-dots are issued inside step t to hide the swizzle/dot latency of t+1.
// ---------------------------------------------------------------------------
__global__ __launch_bounds__(64, 1) void gru_kernel(
    const float* __restrict__ A, const float* __restrict__ B,
    const float* __restrict__ wih, const float* __restrict__ whh,
    const float* __restrict__ bih, const float* __restrict__ bhh,
    float* __restrict__ h_out) {
    const int l = threadIdx.x;                 // 0..63
    const int m = l & 31;
    const int c = (blockIdx.x << 1) | (l >> 5);  // global chain id

    // f16-packed gate rows for hidden index m (96 VGPRs)
    unsigned wXr[16], wXz[16], wXn[16], wHr[16], wHz[16], wHn[16];
#pragma unroll
    for (int k = 0; k < 16; ++k) {
        wXr[k] = pkh(wih[m * 32 + 2 * k],        wih[m * 32 + 2 * k + 1]);
        wXz[k] = pkh(wih[(32 + m) * 32 + 2 * k], wih[(32 + m) * 32 + 2 * k + 1]);
        wXn[k] = pkh(wih[(64 + m) * 32 + 2 * k], wih[(64 + m) * 32 + 2 * k + 1]);
        wHr[k] = pkh(whh[m * 32 + 2 * k],        whh[m * 32 + 2 * k + 1]);
        wHz[k] = pkh(whh[(32 + m) * 32 + 2 * k], whh[(32 + m) * 32 + 2 * k + 1]);
        wHn[k] = pkh(whh[(64 + m) * 32 + 2 * k], whh[(64 + m) * 32 + 2 * k + 1]);
    }
    const float br  = bih[m] + bhh[m];           // full r bias (seeds x-acc)
    const float bz  = bih[32 + m] + bhh[32 + m]; // full z bias
    const float bxn = bih[64 + m];               // n-gate x bias
    const float bhn = bhh[64 + m];               // n-gate h bias

    const float a_r = A[c * 32 + m];             // chain-specific
    float h_l = 0.f;                             // h_m, in-lane

    unsigned hu2[16], ou2[16];
#pragma unroll
    for (int k = 0; k < 16; ++k) hu2[k] = 0u;

    // ---- prologue: X-gates for t=0 ----
    float xr, xz, xn;
    {
        float o0 = fmaxf(a_r + B[m], 0.f);
        unsigned opk = pkh(o0, nbr1(o0));        // even lanes hold pair j=m/2
        BCAST16(ou2, opk);
        xr = br; xz = bz; xn = bxn;
#pragma unroll
        for (int k = 0; k < 16; ++k) {
            xr = d2(wXr[k], ou2[k], xr);
            xz = d2(wXz[k], ou2[k], xz);
            xn = d2(wXn[k], ou2[k], xn);
        }
    }
    float b_next = B[32 + m];                    // B row for t=1

    for (int t = 0; t < 1024; ++t) {
        // global prefetch of B row t+2 (2 steps to land)
        float b_pref = B[((t + 2) & 1023) * 32 + m];

        // issue o-broadcast for step t+1 early (independent of h)
        float onext = fmaxf(a_r + b_next, 0.f);
        unsigned opk = pkh(onext, nbr1(onext));
        BCAST16(ou2, opk);

        // H-dots for step t (hu2 ready from previous iteration's swizzles)
        float hr = 0.f, hz = 0.f, hn = bhn;
#pragma unroll
        for (int k = 0; k < 16; ++k) {
            hr = d2(wHr[k], hu2[k], hr);
            hz = d2(wHz[k], hu2[k], hz);
            hn = d2(wHn[k], hu2[k], hn);
        }

        // gates, fully in-lane
        float r = 1.f / (1.f + __expf(-(xr + hr)));
        float z = 1.f / (1.f + __expf(-(xz + hz)));
        float npre = xn + r * hn;
        float n = 1.f - 2.f / (__expf(2.f * npre) + 1.f);   // tanh
        h_l = (1.f - z) * n + z * h_l;

        // broadcast new h for step t+1
        unsigned hpk = pkh(h_l, nbr1(h_l));
        BCAST16(hu2, hpk);

        // X-dots for step t+1 (fills the h-swizzle latency window)
        float nxr = br, nxz = bz, nxn = bxn;
#pragma unroll
        for (int k = 0; k < 16; ++k) {
            nxr = d2(wXr[k], ou2[k], nxr);
            nxz = d2(wXz[k], ou2[k], nxz);
            nxn = d2(wXn[k], ou2[k], nxn);
        }
        xr = nxr; xz = nxz; xn = nxn;
        b_next = b_pref;
    }

    h_out[c * 32 + m] = h_l;                     // every lane owns (c,m)
}

// ---------------------------------------------------------------------------
// K5: classifier. out[i,o] = sum_k clf_w[o,k]*h2[i,k] + clf_b[o]  (fp32 out)
// ---------------------------------------------------------------------------
__global__ void clf_kernel(const float* __restrict__ h2v, const float* __restrict__ w,
                           const float* __restrict__ bias, float* __restrict__ out) {
    int idx = blockIdx.x * 256 + threadIdx.x;      // 0..3071
    if (idx >= 3072) return;
    int i = idx / 3, o = idx - i * 3;
    float s = bias[o];
#pragma unroll
    for (int k = 0; k < 32; ++k) s += w[o * 32 + k] * h2v[i * 32 + k];
    out[idx] = s;
}

extern "C" void kernel_launch(void* const* d_in, const int* in_sizes, int n_in,
                              void* d_out, int out_size, void* d_ws, size_t ws_size,
                              hipStream_t stream) {
    const float* x       = (const float*)d_in[0];
    const float* p1w     = (const float*)d_in[1];
    const float* p1b     = (const float*)d_in[2];
    const float* g1_wih  = (const float*)d_in[3];
    const float* g1_whh  = (const float*)d_in[4];
    const float* g1_bih  = (const float*)d_in[5];
    const float* g1_bhh  = (const float*)d_in[6];
    const float* p2w     = (const float*)d_in[7];
    const float* p2b     = (const float*)d_in[8];
    const float* g2_wih  = (const float*)d_in[9];
    const float* g2_whh  = (const float*)d_in[10];
    const float* g2_bih  = (const float*)d_in[11];
    const float* g2_bhh  = (const float*)d_in[12];
    const float* clfw    = (const float*)d_in[13];
    const float* clfb    = (const float*)d_in[14];

    // Workspace layout (reused across stages; 3 x 32768 floats = 384 KB):
    float* ws = (float*)d_ws;
    float* A  = ws;              // A1 then A2
    float* Bt = ws + 32768;      // B1 then B2
    float* h  = ws + 65536;      // h1 then h2

    proj1_kernel<<<128, 256, 0, stream>>>(x, p1w, p1b, A, Bt);
    gru_kernel<<<512, 64, 0, stream>>>(A, Bt, g1_wih, g1_whh, g1_bih, g1_bhh, h);
    proj2_kernel<<<128, 256, 0, stream>>>(h, p2w, p2b, A, Bt);
    gru_kernel<<<512, 64, 0, stream>>>(A, Bt, g2_wih, g2_whh, g2_bih, g2_bhh, h);
    clf_kernel<<<12, 256, 0, stream>>>(h, clfw, clfb, (float*)d_out);
}